// Round 3
// baseline (345.525 us; speedup 1.0000x reference)
//
#include <hip/hip_runtime.h>

#define GSZ   16
#define NVOX  4096        // 16^3
#define BB    4
#define DD    128
#define PThr  1024        // prep threads
#define PPT   4           // points per prep thread
#define PTILE (PThr * PPT) // 4096 points per prep tile
#define NDMY  64          // dummy accumulator slots for masked points

typedef __fp16 half2v __attribute__((ext_vector_type(2)));

// packed f16 LDS atomic add: adds (va,vb) to the half2 at LDS byte offset.
__device__ __forceinline__ void lds_pk_add_f16(unsigned byte_off, float va, float vb) {
    half2v h = __builtin_amdgcn_cvt_pkrtz(va, vb);
    unsigned hv;
    __builtin_memcpy(&hv, &h, 4);
    asm volatile("ds_pk_add_f16 %0, %1" : : "v"(byte_off), "v"(hv) : "memory");
}

// ---------------------------------------------------------------------------
// Dispatch 1: voxel idx per point (u16, 0xFFFF = masked) + per-tile u16
// histograms written with plain stores (no global zero-init needed anywhere).
// ---------------------------------------------------------------------------
__global__ __launch_bounds__(PThr) void k_prep(const float* __restrict__ xyz,
                                               const int* __restrict__ mask,
                                               unsigned short* __restrict__ idxm,
                                               unsigned short* __restrict__ histg,
                                               int N, int NT) {
    __shared__ unsigned int hist[NVOX];
    const int tile = blockIdx.x, b = blockIdx.y;
    for (int j = threadIdx.x; j < NVOX; j += PThr) hist[j] = 0u;
    __syncthreads();

    const float*    xb = xyz  + (size_t)b * N * 3;
    const int*      mb = mask + (size_t)b * N;
    unsigned short* ib = idxm + (size_t)b * N;

    const int p0 = tile * PTILE + (int)threadIdx.x * PPT;

    if (p0 + PPT <= N) {
        float a[3 * PPT];
        float4* av = (float4*)a;
        const float4* xv = (const float4*)(xb + 3 * (size_t)p0);
#pragma unroll
        for (int q = 0; q < 3; q++) av[q] = xv[q];
        int4 m4 = *(const int4*)(mb + p0);
        int mk[PPT] = { m4.x, m4.y, m4.z, m4.w };
        alignas(8) unsigned short pk[PPT];
#pragma unroll
        for (int k = 0; k < PPT; k++) {
            int vx = min(max((int)(a[3*k+0] * (float)GSZ), 0), GSZ - 1);
            int vy = min(max((int)(a[3*k+1] * (float)GSZ), 0), GSZ - 1);
            int vz = min(max((int)(a[3*k+2] * (float)GSZ), 0), GSZ - 1);
            int idx = vz * GSZ * GSZ + vy * GSZ + vx;
            if (mk[k] != 0) {
                pk[k] = (unsigned short)idx;
                atomicAdd(&hist[idx], 1u);
            } else {
                pk[k] = 0xFFFFu;
            }
        }
        *(uint2*)(ib + p0) = *(const uint2*)pk;
    } else {
        for (int k = 0; k < PPT; k++) {
            int p = p0 + k;
            if (p >= N) break;
            float x = xb[3*(size_t)p+0], y = xb[3*(size_t)p+1], z = xb[3*(size_t)p+2];
            int vx = min(max((int)(x * (float)GSZ), 0), GSZ - 1);
            int vy = min(max((int)(y * (float)GSZ), 0), GSZ - 1);
            int vz = min(max((int)(z * (float)GSZ), 0), GSZ - 1);
            int idx = vz * GSZ * GSZ + vy * GSZ + vx;
            if (mb[p] != 0) { ib[p] = (unsigned short)idx; atomicAdd(&hist[idx], 1u); }
            else            { ib[p] = 0xFFFFu; }
        }
    }
    __syncthreads();
    unsigned short* hg = histg + ((size_t)b * NT + tile) * NVOX;
    for (int j = threadIdx.x; j < NVOX; j += PThr) hg[j] = (unsigned short)hist[j];
}

// ---------------------------------------------------------------------------
// Dispatch 2: each block owns a (b, d-pair). half2 accumulator in LDS (16 KB)
// plus a 64-slot dummy region: masked points add (branch-free, cndmask'd
// address) into per-lane dummy slots that are never read. One ds_pk_add_f16
// per (point, d-pair). Counts derived per block by summing tile histograms
// (overlaps atomic drain). Flush = coalesced float4 stores with fused divide.
// ---------------------------------------------------------------------------
__global__ __launch_bounds__(1024) void k_scatter(const float* __restrict__ feats,
                                                  const unsigned short* __restrict__ idxm,
                                                  const unsigned short* __restrict__ histg,
                                                  float* __restrict__ out, int N, int NT) {
    __shared__ half2v acc[NVOX + NDMY];  // 16 KB + 256 B
    const int dp = blockIdx.x & 63;      // DD/2 == 64
    const int b  = blockIdx.x >> 6;
    const int d0 = dp * 2;

    {
        half2v z = { (__fp16)0.f, (__fp16)0.f };
        for (int j = threadIdx.x; j < NVOX + NDMY; j += 1024) acc[j] = z;
    }
    __syncthreads();

    const unsigned short* ib = idxm + (size_t)b * N;
    const float* f0 = feats + ((size_t)b * DD + (size_t)d0) * (size_t)N;
    const float* f1 = f0 + N;
    const unsigned accbase = (unsigned)(size_t)(void*)&acc[0];
    const unsigned dmy = accbase + (unsigned)(NVOX + (threadIdx.x & 63)) * 4u;

#define PROC(idx_, va_, vb_)                                                  \
    {                                                                         \
        unsigned _i   = (idx_);                                               \
        unsigned _off = (_i != 0xFFFFu) ? (accbase + _i * 4u) : dmy;          \
        lds_pk_add_f16(_off, (va_), (vb_));                                   \
    }

    const int stride = 1024 * 8;
    const int niter  = N / stride;
    const int t8     = (int)threadIdx.x * 8;

    if (niter > 0) {
        uint4  iv = *(const uint4*)(ib + t8);
        float4 a0 = *(const float4*)(f0 + t8);
        float4 a1 = *(const float4*)(f0 + t8 + 4);
        float4 b0 = *(const float4*)(f1 + t8);
        float4 b1 = *(const float4*)(f1 + t8 + 4);
        for (int it = 0; it < niter; it++) {
            int inext = (it + 1 < niter) ? (it + 1) * stride + t8 : t8;
            uint4  ivn = *(const uint4*)(ib + inext);
            float4 a0n = *(const float4*)(f0 + inext);
            float4 a1n = *(const float4*)(f0 + inext + 4);
            float4 b0n = *(const float4*)(f1 + inext);
            float4 b1n = *(const float4*)(f1 + inext + 4);

            PROC(iv.x & 0xFFFFu, a0.x, b0.x)
            PROC(iv.x >> 16,     a0.y, b0.y)
            PROC(iv.y & 0xFFFFu, a0.z, b0.z)
            PROC(iv.y >> 16,     a0.w, b0.w)
            PROC(iv.z & 0xFFFFu, a1.x, b1.x)
            PROC(iv.z >> 16,     a1.y, b1.y)
            PROC(iv.w & 0xFFFFu, a1.z, b1.z)
            PROC(iv.w >> 16,     a1.w, b1.w)

            iv = ivn; a0 = a0n; a1 = a1n; b0 = b0n; b1 = b1n;
        }
    }
    for (int p = niter * stride + (int)threadIdx.x; p < N; p += 1024) {
        unsigned id  = ib[p];
        unsigned off = (id != 0xFFFFu) ? (accbase + id * 4u) : dmy;
        lds_pk_add_f16(off, f0[p], f1[p]);
    }
#undef PROC

    // sum per-voxel counts from tile histograms while LDS atomics drain
    const int v0 = (int)threadIdx.x * 4;        // 1024 * 4 == NVOX
    int c0 = 0, c1 = 0, c2 = 0, c3 = 0;
    {
        const unsigned short* hb = histg + (size_t)b * NT * NVOX + v0;
        for (int t = 0; t < NT; t++) {
            ushort4 h = *(const ushort4*)(hb + (size_t)t * NVOX);
            c0 += h.x; c1 += h.y; c2 += h.z; c3 += h.w;
        }
    }
    __syncthreads();

    half2v s0 = acc[v0+0], s1 = acc[v0+1], s2 = acc[v0+2], s3 = acc[v0+3];
    float i0 = 1.f / (float)max(c0, 1);
    float i1 = 1.f / (float)max(c1, 1);
    float i2 = 1.f / (float)max(c2, 1);
    float i3 = 1.f / (float)max(c3, 1);
    float4 oa, ob;
    oa.x = (float)s0.x * i0;  ob.x = (float)s0.y * i0;
    oa.y = (float)s1.x * i1;  ob.y = (float)s1.y * i1;
    oa.z = (float)s2.x * i2;  ob.z = (float)s2.y * i2;
    oa.w = (float)s3.x * i3;  ob.w = (float)s3.y * i3;
    float* r0 = out + ((size_t)b * DD + (size_t)d0) * (size_t)NVOX + v0;
    *(float4*)r0          = oa;
    *(float4*)(r0 + NVOX) = ob;
}

extern "C" void kernel_launch(void* const* d_in, const int* in_sizes, int n_in,
                              void* d_out, int out_size, void* d_ws, size_t ws_size,
                              hipStream_t stream) {
    const float* feats = (const float*)d_in[0];          // [B, D, N]
    const float* xyz   = (const float*)d_in[1];          // [B, N, 3]
    const int*   mask  = (const int*)d_in[2];            // [B, N]
    float*       out   = (float*)d_out;                  // [B, D, V]

    int N  = in_sizes[2] / BB;                           // mask is B*N
    int NT = (N + PTILE - 1) / PTILE;

    // workspace carve — everything fully overwritten each call, no memsets
    char* w = (char*)d_ws;
    unsigned short* idxm  = (unsigned short*)w;          // B*N u16
    w += (((size_t)BB * N * sizeof(unsigned short)) + 255) & ~(size_t)255;
    unsigned short* histg = (unsigned short*)w;          // B*NT*NVOX u16

    k_prep   <<<dim3(NT, BB), PThr, 0, stream>>>(xyz, mask, idxm, histg, N, NT);
    k_scatter<<<BB * (DD / 2), 1024, 0, stream>>>(feats, idxm, histg, out, N, NT);
}

// Round 4
// 312.335 us; speedup vs baseline: 1.1063x; 1.1063x over previous
//
#include <hip/hip_runtime.h>

#define GSZ   16
#define NVOX  4096        // 16^3
#define BB    4
#define DD    128
#define PThr  1024        // prep threads
#define PPT   4           // points per prep thread
#define PTILE (PThr * PPT) // 4096 points per prep tile

typedef __fp16 half2v __attribute__((ext_vector_type(2)));

// packed f16 LDS atomic add: adds (va,vb) to the half2 at LDS byte offset.
__device__ __forceinline__ void lds_pk_add_f16(unsigned byte_off, float va, float vb) {
    half2v h = __builtin_amdgcn_cvt_pkrtz(va, vb);
    unsigned hv;
    __builtin_memcpy(&hv, &h, 4);
    asm volatile("ds_pk_add_f16 %0, %1" : : "v"(byte_off), "v"(hv) : "memory");
}

// ---------------------------------------------------------------------------
// Dispatch 1: per-tile ACTIVE-POINT COMPACTION + per-tile u16 histograms.
// Each tile (4096 pts) emits centry[j] = voxidx | (local_off<<16) for its
// active points (count in tcnt). Scatter then runs with zero masked lanes.
// ---------------------------------------------------------------------------
__global__ __launch_bounds__(PThr) void k_prep(const float* __restrict__ xyz,
                                               const int* __restrict__ mask,
                                               unsigned int* __restrict__ centry,
                                               unsigned int* __restrict__ tcnt,
                                               unsigned short* __restrict__ histg,
                                               int N, int NT) {
    __shared__ unsigned int hist[NVOX];
    __shared__ int wsum[16], wbase[16];
    const int tile = blockIdx.x, b = blockIdx.y;
    for (int j = threadIdx.x; j < NVOX; j += PThr) hist[j] = 0u;
    __syncthreads();

    const float* xb = xyz  + (size_t)b * N * 3;
    const int*   mb = mask + (size_t)b * N;

    const int p0 = tile * PTILE + (int)threadIdx.x * PPT;

    int           act[PPT];
    unsigned int  vidx[PPT];

    if (p0 + PPT <= N) {
        float a[3 * PPT];
        float4* av = (float4*)a;
        const float4* xv = (const float4*)(xb + 3 * (size_t)p0);
#pragma unroll
        for (int q = 0; q < 3; q++) av[q] = xv[q];
        int4 m4 = *(const int4*)(mb + p0);
        int mk[PPT] = { m4.x, m4.y, m4.z, m4.w };
#pragma unroll
        for (int k = 0; k < PPT; k++) {
            int vx = min(max((int)(a[3*k+0] * (float)GSZ), 0), GSZ - 1);
            int vy = min(max((int)(a[3*k+1] * (float)GSZ), 0), GSZ - 1);
            int vz = min(max((int)(a[3*k+2] * (float)GSZ), 0), GSZ - 1);
            unsigned idx = (unsigned)(vz * GSZ * GSZ + vy * GSZ + vx);
            vidx[k] = idx;
            act[k]  = (mk[k] != 0) ? 1 : 0;
            if (act[k]) atomicAdd(&hist[idx], 1u);
        }
    } else {
#pragma unroll
        for (int k = 0; k < PPT; k++) {
            int p = p0 + k;
            if (p < N) {
                float x = xb[3*(size_t)p+0], y = xb[3*(size_t)p+1], z = xb[3*(size_t)p+2];
                int vx = min(max((int)(x * (float)GSZ), 0), GSZ - 1);
                int vy = min(max((int)(y * (float)GSZ), 0), GSZ - 1);
                int vz = min(max((int)(z * (float)GSZ), 0), GSZ - 1);
                unsigned idx = (unsigned)(vz * GSZ * GSZ + vy * GSZ + vx);
                vidx[k] = idx;
                act[k]  = (mb[p] != 0) ? 1 : 0;
                if (act[k]) atomicAdd(&hist[idx], 1u);
            } else {
                vidx[k] = 0u; act[k] = 0;
            }
        }
    }

    // ---- block-wide exclusive scan of per-thread active counts ----
    const int lane = (int)threadIdx.x & 63;
    const int wid  = (int)threadIdx.x >> 6;      // 16 waves
    int mcnt = act[0] + act[1] + act[2] + act[3];
    int v = mcnt;
#pragma unroll
    for (int d = 1; d < 64; d <<= 1) {
        int t = __shfl_up(v, d, 64);
        if (lane >= d) v += t;
    }
    if (lane == 63) wsum[wid] = v;               // wave totals
    __syncthreads();
    if (threadIdx.x < 16) {
        int s = wsum[threadIdx.x];
        int e = s;
#pragma unroll
        for (int d = 1; d < 16; d <<= 1) {
            int t = __shfl_up(e, d, 16);
            if (((int)threadIdx.x & 15) >= d) e += t;
        }
        wbase[threadIdx.x] = e - s;              // exclusive wave base
        if (threadIdx.x == 15) tcnt[(size_t)b * NT + tile] = (unsigned)e;
    }
    __syncthreads();

    int off = wbase[wid] + (v - mcnt);           // thread's exclusive offset
    unsigned int* cb = centry + ((size_t)b * NT + tile) * PTILE;
#pragma unroll
    for (int k = 0; k < PPT; k++) {
        if (act[k]) {
            unsigned local = (unsigned)((int)threadIdx.x * PPT + k);
            cb[off++] = vidx[k] | (local << 16);
        }
    }

    __syncthreads();
    unsigned short* hg = histg + ((size_t)b * NT + tile) * NVOX;
    for (int j = threadIdx.x; j < NVOX; j += PThr) hg[j] = (unsigned short)hist[j];
}

// ---------------------------------------------------------------------------
// Dispatch 2: each block owns a (b, d-pair). half2 accumulator in LDS (16 KB);
// iterates ONLY active compacted points -> one ds_pk_add_f16 per active
// (point, d-pair), all 64 lanes useful, no branches around the atomic.
// Feature reads are ~50%-dense gathers (same cachelines as a full stream).
// Counts summed from tile histograms while the atomic pipe drains.
// ---------------------------------------------------------------------------
__global__ __launch_bounds__(1024) void k_scatter(const float* __restrict__ feats,
                                                  const unsigned int* __restrict__ centry,
                                                  const unsigned int* __restrict__ tcnt,
                                                  const unsigned short* __restrict__ histg,
                                                  float* __restrict__ out, int N, int NT) {
    __shared__ half2v acc[NVOX];     // 16 KB
    const int dp = blockIdx.x & 63;  // DD/2 == 64
    const int b  = blockIdx.x >> 6;
    const int d0 = dp * 2;

    {
        half2v z = { (__fp16)0.f, (__fp16)0.f };
        for (int j = threadIdx.x; j < NVOX; j += 1024) acc[j] = z;
    }
    __syncthreads();

    const unsigned int* ce = centry + (size_t)b * NT * PTILE;
    const unsigned int* tc = tcnt + (size_t)b * NT;
    const float* f0 = feats + ((size_t)b * DD + (size_t)d0) * (size_t)N;
    const float* f1 = f0 + N;
    const unsigned accbase = (unsigned)(size_t)(void*)&acc[0];

    for (int t = 0; t < NT; t++) {
        const int n = (int)tc[t];                       // uniform -> scalar
        const unsigned int* cb = ce + (size_t)t * PTILE;
        const float* g0 = f0 + t * PTILE;
        const float* g1 = f1 + t * PTILE;
        for (int j = (int)threadIdx.x; j < n; j += 1024) {
            unsigned e   = cb[j];
            unsigned idx = e & 0xFFFFu;
            unsigned off = e >> 16;
            lds_pk_add_f16(accbase + idx * 4u, g0[off], g1[off]);
        }
    }

    // sum per-voxel counts from tile histograms while LDS atomics drain
    const int v0 = (int)threadIdx.x * 4;        // 1024 * 4 == NVOX
    int c0 = 0, c1 = 0, c2 = 0, c3 = 0;
    {
        const unsigned short* hb = histg + (size_t)b * NT * NVOX + v0;
        for (int t = 0; t < NT; t++) {
            ushort4 h = *(const ushort4*)(hb + (size_t)t * NVOX);
            c0 += h.x; c1 += h.y; c2 += h.z; c3 += h.w;
        }
    }
    __syncthreads();

    half2v s0 = acc[v0+0], s1 = acc[v0+1], s2 = acc[v0+2], s3 = acc[v0+3];
    float i0 = 1.f / (float)max(c0, 1);
    float i1 = 1.f / (float)max(c1, 1);
    float i2 = 1.f / (float)max(c2, 1);
    float i3 = 1.f / (float)max(c3, 1);
    float4 oa, ob;
    oa.x = (float)s0.x * i0;  ob.x = (float)s0.y * i0;
    oa.y = (float)s1.x * i1;  ob.y = (float)s1.y * i1;
    oa.z = (float)s2.x * i2;  ob.z = (float)s2.y * i2;
    oa.w = (float)s3.x * i3;  ob.w = (float)s3.y * i3;
    float* r0 = out + ((size_t)b * DD + (size_t)d0) * (size_t)NVOX + v0;
    *(float4*)r0          = oa;
    *(float4*)(r0 + NVOX) = ob;
}

extern "C" void kernel_launch(void* const* d_in, const int* in_sizes, int n_in,
                              void* d_out, int out_size, void* d_ws, size_t ws_size,
                              hipStream_t stream) {
    const float* feats = (const float*)d_in[0];          // [B, D, N]
    const float* xyz   = (const float*)d_in[1];          // [B, N, 3]
    const int*   mask  = (const int*)d_in[2];            // [B, N]
    float*       out   = (float*)d_out;                  // [B, D, V]

    int N  = in_sizes[2] / BB;                           // mask is B*N
    int NT = (N + PTILE - 1) / PTILE;

    // workspace carve — scatter only reads bytes prep wrote this call
    char* w = (char*)d_ws;
    unsigned int*   centry = (unsigned int*)w;           // B*NT*PTILE u32 (~1.6 MB)
    w += (((size_t)BB * NT * PTILE * sizeof(unsigned int)) + 255) & ~(size_t)255;
    unsigned int*   tcnt   = (unsigned int*)w;           // B*NT u32
    w += (((size_t)BB * NT * sizeof(unsigned int)) + 255) & ~(size_t)255;
    unsigned short* histg  = (unsigned short*)w;         // B*NT*NVOX u16 (~800 KB)

    k_prep   <<<dim3(NT, BB), PThr, 0, stream>>>(xyz, mask, centry, tcnt, histg, N, NT);
    k_scatter<<<BB * (DD / 2), 1024, 0, stream>>>(feats, centry, tcnt, histg, out, N, NT);
}

// Round 5
// 296.630 us; speedup vs baseline: 1.1648x; 1.0529x over previous
//
#include <hip/hip_runtime.h>

#define GSZ   16
#define NVOX  4096        // 16^3
#define BB    4
#define DD    128
#define PThr  1024        // prep threads
#define PPT   4           // points per prep thread
#define PTILE (PThr * PPT) // 4096 points per prep tile
#define FSCALE 32768.0f   // 2^15 fixed-point scale for i32 accumulation

// ---------------------------------------------------------------------------
// Dispatch 1: voxel idx per point (u16, 0xFFFF = masked) + per-tile u16
// histograms written with plain stores (no global zero-init needed anywhere).
// ---------------------------------------------------------------------------
__global__ __launch_bounds__(PThr) void k_prep(const float* __restrict__ xyz,
                                               const int* __restrict__ mask,
                                               unsigned short* __restrict__ idxm,
                                               unsigned short* __restrict__ histg,
                                               int N, int NT) {
    __shared__ unsigned int hist[NVOX];
    const int tile = blockIdx.x, b = blockIdx.y;
    for (int j = threadIdx.x; j < NVOX; j += PThr) hist[j] = 0u;
    __syncthreads();

    const float*    xb = xyz  + (size_t)b * N * 3;
    const int*      mb = mask + (size_t)b * N;
    unsigned short* ib = idxm + (size_t)b * N;

    const int p0 = tile * PTILE + (int)threadIdx.x * PPT;

    if (p0 + PPT <= N) {
        float a[3 * PPT];
        float4* av = (float4*)a;
        const float4* xv = (const float4*)(xb + 3 * (size_t)p0);
#pragma unroll
        for (int q = 0; q < 3; q++) av[q] = xv[q];
        int4 m4 = *(const int4*)(mb + p0);
        int mk[PPT] = { m4.x, m4.y, m4.z, m4.w };
        alignas(8) unsigned short pk[PPT];
#pragma unroll
        for (int k = 0; k < PPT; k++) {
            int vx = min(max((int)(a[3*k+0] * (float)GSZ), 0), GSZ - 1);
            int vy = min(max((int)(a[3*k+1] * (float)GSZ), 0), GSZ - 1);
            int vz = min(max((int)(a[3*k+2] * (float)GSZ), 0), GSZ - 1);
            int idx = vz * GSZ * GSZ + vy * GSZ + vx;
            if (mk[k] != 0) {
                pk[k] = (unsigned short)idx;
                atomicAdd(&hist[idx], 1u);
            } else {
                pk[k] = 0xFFFFu;
            }
        }
        *(uint2*)(ib + p0) = *(const uint2*)pk;
    } else {
        for (int k = 0; k < PPT; k++) {
            int p = p0 + k;
            if (p >= N) break;
            float x = xb[3*(size_t)p+0], y = xb[3*(size_t)p+1], z = xb[3*(size_t)p+2];
            int vx = min(max((int)(x * (float)GSZ), 0), GSZ - 1);
            int vy = min(max((int)(y * (float)GSZ), 0), GSZ - 1);
            int vz = min(max((int)(z * (float)GSZ), 0), GSZ - 1);
            int idx = vz * GSZ * GSZ + vy * GSZ + vx;
            if (mb[p] != 0) { ib[p] = (unsigned short)idx; atomicAdd(&hist[idx], 1u); }
            else            { ib[p] = 0xFFFFu; }
        }
    }
    __syncthreads();
    unsigned short* hg = histg + ((size_t)b * NT + tile) * NVOX;
    for (int j = threadIdx.x; j < NVOX; j += PThr) hg[j] = (unsigned short)hist[j];
}

// ---------------------------------------------------------------------------
// Dispatch 2: each block owns a (b, d-pair). i32 FIXED-POINT accumulator in
// LDS (32 KB, interleaved [2v], [2v+1]); two int atomicAdds (ds_add_u32,
// per-bank integer atomic hardware) per active point. Exec-masked skip for
// inactive points. Counts summed from tile histograms while atomics drain.
// ---------------------------------------------------------------------------
__global__ __launch_bounds__(1024) void k_scatter(const float* __restrict__ feats,
                                                  const unsigned short* __restrict__ idxm,
                                                  const unsigned short* __restrict__ histg,
                                                  float* __restrict__ out, int N, int NT) {
    __shared__ int acc[2 * NVOX];    // 32 KB
    const int dp = blockIdx.x & 63;  // DD/2 == 64
    const int b  = blockIdx.x >> 6;
    const int d0 = dp * 2;

    for (int j = threadIdx.x; j < 2 * NVOX; j += 1024) acc[j] = 0;
    __syncthreads();

    const unsigned short* ib = idxm + (size_t)b * N;
    const float* f0 = feats + ((size_t)b * DD + (size_t)d0) * (size_t)N;
    const float* f1 = f0 + N;

#define PROC(idx_, va_, vb_)                                          \
    {                                                                 \
        unsigned _i = (idx_);                                         \
        if (_i != 0xFFFFu) {                                          \
            atomicAdd(&acc[2u * _i],     __float2int_rn((va_) * FSCALE)); \
            atomicAdd(&acc[2u * _i + 1], __float2int_rn((vb_) * FSCALE)); \
        }                                                             \
    }

    const int stride = 1024 * 8;
    const int niter  = N / stride;
    const int t8     = (int)threadIdx.x * 8;

    if (niter > 0) {
        uint4  iv = *(const uint4*)(ib + t8);
        float4 a0 = *(const float4*)(f0 + t8);
        float4 a1 = *(const float4*)(f0 + t8 + 4);
        float4 b0 = *(const float4*)(f1 + t8);
        float4 b1 = *(const float4*)(f1 + t8 + 4);
        for (int it = 0; it < niter; it++) {
            int inext = (it + 1 < niter) ? (it + 1) * stride + t8 : t8;
            uint4  ivn = *(const uint4*)(ib + inext);
            float4 a0n = *(const float4*)(f0 + inext);
            float4 a1n = *(const float4*)(f0 + inext + 4);
            float4 b0n = *(const float4*)(f1 + inext);
            float4 b1n = *(const float4*)(f1 + inext + 4);

            PROC(iv.x & 0xFFFFu, a0.x, b0.x)
            PROC(iv.x >> 16,     a0.y, b0.y)
            PROC(iv.y & 0xFFFFu, a0.z, b0.z)
            PROC(iv.y >> 16,     a0.w, b0.w)
            PROC(iv.z & 0xFFFFu, a1.x, b1.x)
            PROC(iv.z >> 16,     a1.y, b1.y)
            PROC(iv.w & 0xFFFFu, a1.z, b1.z)
            PROC(iv.w >> 16,     a1.w, b1.w)

            iv = ivn; a0 = a0n; a1 = a1n; b0 = b0n; b1 = b1n;
        }
    }
    for (int p = niter * stride + (int)threadIdx.x; p < N; p += 1024) {
        unsigned id = ib[p];
        if (id != 0xFFFFu) {
            atomicAdd(&acc[2u * id],     __float2int_rn(f0[p] * FSCALE));
            atomicAdd(&acc[2u * id + 1], __float2int_rn(f1[p] * FSCALE));
        }
    }
#undef PROC

    // sum per-voxel counts from tile histograms while LDS atomics drain
    const int v0 = (int)threadIdx.x * 4;        // 1024 * 4 == NVOX
    int c0 = 0, c1 = 0, c2 = 0, c3 = 0;
    {
        const unsigned short* hb = histg + (size_t)b * NT * NVOX + v0;
        for (int t = 0; t < NT; t++) {
            ushort4 h = *(const ushort4*)(hb + (size_t)t * NVOX);
            c0 += h.x; c1 += h.y; c2 += h.z; c3 += h.w;
        }
    }
    __syncthreads();

    int4 s01 = *(const int4*)&acc[2 * v0 + 0];   // v0,v0+1
    int4 s23 = *(const int4*)&acc[2 * v0 + 4];   // v0+2,v0+3
    const float r = 1.0f / FSCALE;
    float i0 = r / (float)max(c0, 1);
    float i1 = r / (float)max(c1, 1);
    float i2 = r / (float)max(c2, 1);
    float i3 = r / (float)max(c3, 1);
    float4 oa, ob;
    oa.x = (float)s01.x * i0;  ob.x = (float)s01.y * i0;
    oa.y = (float)s01.z * i1;  ob.y = (float)s01.w * i1;
    oa.z = (float)s23.x * i2;  ob.z = (float)s23.y * i2;
    oa.w = (float)s23.z * i3;  ob.w = (float)s23.w * i3;
    float* r0 = out + ((size_t)b * DD + (size_t)d0) * (size_t)NVOX + v0;
    *(float4*)r0          = oa;
    *(float4*)(r0 + NVOX) = ob;
}

extern "C" void kernel_launch(void* const* d_in, const int* in_sizes, int n_in,
                              void* d_out, int out_size, void* d_ws, size_t ws_size,
                              hipStream_t stream) {
    const float* feats = (const float*)d_in[0];          // [B, D, N]
    const float* xyz   = (const float*)d_in[1];          // [B, N, 3]
    const int*   mask  = (const int*)d_in[2];            // [B, N]
    float*       out   = (float*)d_out;                  // [B, D, V]

    int N  = in_sizes[2] / BB;                           // mask is B*N
    int NT = (N + PTILE - 1) / PTILE;

    // workspace carve — everything fully overwritten each call, no memsets
    char* w = (char*)d_ws;
    unsigned short* idxm  = (unsigned short*)w;          // B*N u16
    w += (((size_t)BB * N * sizeof(unsigned short)) + 255) & ~(size_t)255;
    unsigned short* histg = (unsigned short*)w;          // B*NT*NVOX u16

    k_prep   <<<dim3(NT, BB), PThr, 0, stream>>>(xyz, mask, idxm, histg, N, NT);
    k_scatter<<<BB * (DD / 2), 1024, 0, stream>>>(feats, idxm, histg, out, N, NT);
}